// Round 4
// baseline (679.339 us; speedup 1.0000x reference)
//
#include <hip/hip_runtime.h>

typedef _Float16 f16x8 __attribute__((ext_vector_type(8)));
typedef float f32x4 __attribute__((ext_vector_type(4)));

#define Dd 256
#define Hh 1024

// ---------- prep: pack weights fragment-major for the 16-wave layout ----------
// W1P tile (w,kk,nt) = ((w*8+kk)*4+nt): lane(q*16+ln)*8+j holds
//   W1[kk*32+q*8+j][w*64+nt*16+ln]  (B-fragment for 16x16x32 MFMA).
// kk-major chunking: chunk = 4 nt-tiles at one kk => one shared A-fragment
// per chunk, 4 independent accumulators (no intra-chunk acc chain).
__global__ void pack_w1_kernel(const float* __restrict__ W1, _Float16* __restrict__ W1P) {
    int gid = blockIdx.x * 256 + threadIdx.x;       // 256*1024 elements
    int h = gid & 1023, d = gid >> 10;
    int w = h >> 6, nt = (h >> 4) & 3, ln = h & 15;
    int kk = d >> 5, q = (d >> 3) & 3, j = d & 7;
    W1P[(((w * 8 + kk) * 4 + nt) * 64 + q * 16 + ln) * 8 + j] = (_Float16)W1[d * 1024 + h];
}
// W2P tile (w,kk) = (w*32+kk): wave w owns D-cols [w*16,+16); kk in [0,32).
__global__ void pack_w2_kernel(const float* __restrict__ W2, _Float16* __restrict__ W2P) {
    int gid = blockIdx.x * 256 + threadIdx.x;       // 1024*256 elements
    int dcol = gid & 255, h = gid >> 8;
    int w = dcol >> 4, ln = dcol & 15;
    int kk = h >> 5, q = (h >> 3) & 3, j = h & 7;
    W2P[((w * 32 + kk) * 64 + q * 16 + ln) * 8 + j] = (_Float16)W2[h * 256 + dcol];
}

// ---------------- main: 64 blocks x 1024 thr (16 waves), register weight ring ----------------
// Rounds 0-3 post-mortem: every schedule variant (LDS ring, 8/4-slot register
// ring) lands at ~15 us/eval = 1 MB/eval/CU / ~30 B/cyc. Weights are
// L2-resident (all blocks read the same 1 MB), so this is a latency*outstanding
// limit, and per-CU fetch BW scales with resident waves (m56: ~60 B/cyc at
// high occupancy). Same total traffic, twice the waves: 16 waves/CU, each
// owning half the old slice (64 H-cols, 16 D-cols), 16 chunks/eval instead of
// 32. Outstanding capacity doubles to 256 KB/CU; per-wave serial chunk chain
// halves. 16 waves/CU = 4 waves/SIMD forces the 128-VGPR cap, and the
// per-wave state now fits it (~130): ring 64 + acc 16+4 + z/zsum 8 + frags 8
// + biases 5 + addressing.
// Accumulation order matches the previously-passing kernel exactly
// (GEMM1: per nt, kk ascending; GEMM2: single chain, kk ascending).
__global__ __launch_bounds__(1024) void ode_kernel(
    const float* __restrict__ z0, const float* __restrict__ tv,
    const float* __restrict__ b1, const float* __restrict__ b2,
    const _Float16* __restrict__ W1P, const _Float16* __restrict__ W2P,
    float* __restrict__ out) {
    __shared__ _Float16 act_lds[16][1032];   // 33 KB (+8 pad)
    __shared__ _Float16 z_lds[16][264];      // 8.25 KB

    const int tid  = threadIdx.x;
    const int w    = tid >> 6;               // 0..15
    const int lane = tid & 63;
    const int ln   = lane & 15;
    const int q    = lane >> 4;
    const int m0   = blockIdx.x * 16;

    const float h = (tv[1] - tv[0]) * 0.125f;

    float bb1[4];
#pragma unroll
    for (int nt = 0; nt < 4; ++nt) bb1[nt] = b1[w * 64 + nt * 16 + ln];
    const float bb2 = b2[w * 16 + ln];

    const _Float16* W1w = W1P + (size_t)w * 16384;   // 32 KB: tiles (kk,nt)
    const _Float16* W2w = W2P + (size_t)w * 16384;   // 32 KB: tiles (kk)

    // 4-slot register ring: 4 x 4 x f16x8 = 64 VGPRs. Global chunk g in
    // [0,16): g<8 => W1 chunk g (kk=g, nt 0..3); g>=8 => W2 chunk g-8
    // (kk = (g-8)*4 .. +3). Slot g&3; issue-after-consume, depth 4
    // (16 KB/wave in flight; 16 waves => 256 KB/CU). 16 % 4 == 0 keeps slot
    // assignment eval-invariant across the backedge.
    f16x8 wb[4][4];

#define ISSUE(gg) { const int cm = (gg) & 15;                                        \
    const _Float16* gsrc = (cm < 8) ? (W1w + cm * 2048) : (W2w + (cm - 8) * 2048);   \
    _Pragma("unroll")                                                                \
    for (int ii = 0; ii < 4; ++ii)                                                   \
        wb[(gg) & 3][ii] = *(const f16x8*)(gsrc + ii * 512 + lane * 8);              \
    __builtin_amdgcn_sched_barrier(0); }

// act/z are LDS-only: lgkmcnt(0) publishes ds_writes, s_barrier syncs waves.
// Deliberately NO vmcnt drain — weight prefetch loads stay in flight.
#define BARRIER() asm volatile("s_waitcnt lgkmcnt(0)\n\ts_barrier" ::: "memory")

    // RK4 state in registers (C-layout): z[r] = z[m0+q*4+r][w*16+ln]
    f32x4 z, zsum;
#pragma unroll
    for (int r = 0; r < 4; ++r)
        z[r] = z0[(m0 + q * 4 + r) * Dd + w * 16 + ln];
#pragma unroll
    for (int r = 0; r < 4; ++r)
        z_lds[q * 4 + r][w * 16 + ln] = (_Float16)z[r];
    __syncthreads();   // full drain once; prologue prefetch issued after it

    ISSUE(0); ISSUE(1); ISSUE(2); ISSUE(3);

#pragma unroll 1
    for (int ev = 0; ev < 32; ++ev) {
        const int e = ev & 3;

        // ---- GEMM1: act[:, w*64..+64) = tanh(z @ W1 + b1) ----
        f32x4 acc[4] = {{0.f,0.f,0.f,0.f},{0.f,0.f,0.f,0.f},
                        {0.f,0.f,0.f,0.f},{0.f,0.f,0.f,0.f}};
#pragma unroll
        for (int g = 0; g < 8; ++g) {        // chunk g: kk=g, one shared A-frag
            f16x8 a1 = *(const f16x8*)&z_lds[ln][g * 32 + q * 8];
#pragma unroll
            for (int nt = 0; nt < 4; ++nt)   // 4 independent acc chains
                acc[nt] = __builtin_amdgcn_mfma_f32_16x16x32_f16(
                    a1, wb[g & 3][nt], acc[nt], 0, 0, 0);
            ISSUE(g + 4);                    // g=4..7 issue W2 chunks 8..11
        }
#pragma unroll
        for (int nt = 0; nt < 4; ++nt)
#pragma unroll
            for (int r = 0; r < 4; ++r) {
                float x = acc[nt][r] + bb1[nt];
                float ex = __expf(2.0f * x);
                act_lds[q * 4 + r][w * 64 + nt * 16 + ln] =
                    (_Float16)(1.0f - 2.0f / (ex + 1.0f));
            }
        BARRIER();   // act visible; W2 chunks 8..11 remain in flight

        // ---- GEMM2: k[:, w*16..+16) = act @ W2 + b2 ----
        f32x4 acc2 = {0.f, 0.f, 0.f, 0.f};
#pragma unroll
        for (int g = 8; g < 16; ++g) {       // chunk g: kk = (g-8)*4 .. +3
#pragma unroll
            for (int i = 0; i < 4; ++i) {
                const int kk = (g - 8) * 4 + i;
                f16x8 a2 = *(const f16x8*)&act_lds[ln][kk * 32 + q * 8];
                acc2 = __builtin_amdgcn_mfma_f32_16x16x32_f16(
                    a2, wb[g & 3][i], acc2, 0, 0, 0);
            }
            ISSUE(g + 4);                    // g=12..15 wrap: next eval chunks 0..3
        }

        // ---- RK4 epilogue (registers) ----
        f32x4 kv, za;
#pragma unroll
        for (int r = 0; r < 4; ++r) kv[r] = acc2[r] + bb2;
        if (e == 0) {
            zsum = kv;
        } else if (e == 3) {
#pragma unroll
            for (int r = 0; r < 4; ++r) zsum[r] += kv[r];
        } else {
#pragma unroll
            for (int r = 0; r < 4; ++r) zsum[r] += 2.0f * kv[r];
        }
        if (e < 3) {
            const float c = (e == 2) ? h : 0.5f * h;
#pragma unroll
            for (int r = 0; r < 4; ++r) za[r] = z[r] + c * kv[r];
        } else {
#pragma unroll
            for (int r = 0; r < 4; ++r) {
                z[r] += (h * (1.0f / 6.0f)) * zsum[r];
                za[r] = z[r];
            }
        }
#pragma unroll
        for (int r = 0; r < 4; ++r)
            z_lds[q * 4 + r][w * 16 + ln] = (_Float16)za[r];
        BARRIER();   // z visible for next eval; wraparound prefetch in flight
    }

#pragma unroll
    for (int r = 0; r < 4; ++r)
        out[(m0 + q * 4 + r) * Dd + w * 16 + ln] = z[r];
#undef ISSUE
#undef BARRIER
}

extern "C" void kernel_launch(void* const* d_in, const int* in_sizes, int n_in,
                              void* d_out, int out_size, void* d_ws, size_t ws_size,
                              hipStream_t stream) {
    const float* z0 = (const float*)d_in[0];
    const float* tv = (const float*)d_in[1];
    const float* W1 = (const float*)d_in[2];   // [256][1024]
    const float* b1 = (const float*)d_in[3];   // [1024]
    const float* W2 = (const float*)d_in[4];   // [1024][256]
    const float* b2 = (const float*)d_in[5];   // [256]
    float* out = (float*)d_out;

    _Float16* W1P = (_Float16*)d_ws;           // 512 KB fragment-major
    _Float16* W2P = W1P + Hh * Dd;             // 512 KB fragment-major

    pack_w1_kernel<<<1024, 256, 0, stream>>>(W1, W1P);
    pack_w2_kernel<<<1024, 256, 0, stream>>>(W2, W2P);

    ode_kernel<<<64, 1024, 0, stream>>>(z0, tv, b1, b2, W1P, W2P, out);
}

// Round 5
// 659.889 us; speedup vs baseline: 1.0295x; 1.0295x over previous
//
#include <hip/hip_runtime.h>

typedef _Float16 f16x8 __attribute__((ext_vector_type(8)));
typedef float f32x4 __attribute__((ext_vector_type(4)));

#define Dd 256
#define Hh 1024

// ---------- prep: pack weights fragment-major for the K=4 split ----------
// Member m owns H-slice [m*256,+256); wave w of member m owns H-cols
// [m*256+w*32,+32) (GEMM1) and D-cols [w*32,+32) (GEMM2).
// W1P tile (m,w,kk,nt) = (((m*8+w)*8+kk)*2+nt): lane(q*16+ln)*8+j holds
//   W1[kk*32+q*8+j][m*256 + w*32 + nt*16 + ln]   (B-frag, 16x16x32)
__global__ void pack_w1_kernel(const float* __restrict__ W1, _Float16* __restrict__ W1P) {
    int gid = blockIdx.x * 256 + threadIdx.x;       // 256*1024 elements
    int h = gid & 1023, d = gid >> 10;
    int m = h >> 8, w = (h >> 5) & 7, nt = (h >> 4) & 1, ln = h & 15;
    int kk = d >> 5, q = (d >> 3) & 3, j = d & 7;
    W1P[((((m * 8 + w) * 8 + kk) * 2 + nt) * 64 + q * 16 + ln) * 8 + j] =
        (_Float16)W1[d * 1024 + h];
}
// W2P tile (m,w,kk,t) = (((m*8+w)*8+kk)*2+t): lane(q*16+ln)*8+j holds
//   W2[m*256 + kk*32 + q*8 + j][w*32 + t*16 + ln]
__global__ void pack_w2_kernel(const float* __restrict__ W2, _Float16* __restrict__ W2P) {
    int gid = blockIdx.x * 256 + threadIdx.x;       // 1024*256 elements
    int dcol = gid & 255, hh = gid >> 8;
    int m = hh >> 8, kk = (hh >> 5) & 7, q = (hh >> 3) & 3, j = hh & 7;
    int w = dcol >> 5, t = (dcol >> 4) & 1, ln = dcol & 15;
    W2P[((((m * 8 + w) * 8 + kk) * 2 + t) * 64 + q * 16 + ln) * 8 + j] =
        (_Float16)W2[hh * 256 + dcol];
}

__global__ void reset_flags_kernel(unsigned* flags) {
    // device-scope RMW so the reset is visible at the coherent point (MALL),
    // not stranded dirty in one XCD's L2 (graph replays reuse the buffer).
    atomicExch(&flags[threadIdx.x], 0u);
}

typedef __attribute__((address_space(1))) const unsigned int gu32;
typedef __attribute__((address_space(3))) unsigned int lu32;
__device__ __forceinline__ void async_tile(const _Float16* g, _Float16* l, int lane) {
    __builtin_amdgcn_global_load_lds((gu32*)(g + lane * 8), (lu32*)l, 16, 0, 0);
}

// ---------------- main: 256 blocks x 512 thr — network split K=4, weights resident ----------------
// Rounds 0-3 evidence: every weight-streaming schedule (LDS ring / register
// ring) converges to ~15 us/eval = 1 MB/eval/CU / ~67 GB/s/CU — a per-CU L2
// streaming roofline. Fix: stop streaming. 4 blocks cooperate per 16-row
// batch group (g = blockIdx&63, m = blockIdx>>6). Member m holds its W1 slice
// in 64 VGPRs (16 fragment tiles) and its W2 slice in 128 KB LDS — per-eval
// weight traffic is ZERO. Per eval: GEMM1 (B from regs), GEMM2 (B from LDS),
// then partial-k exchange through kbuf (global):
//   write own 16x256 f32 partial -> __syncthreads (drains each wave's stores)
//   thread0: __threadfence (release: wbl2 to coherent point) + atomicAdd(flag)
//            spin atomicAdd(flag,0) >= 4*(ev+1)  (device-scope RMW: coherent)
//            __threadfence (acquire: inv stale L1/L2)
//   __syncthreads -> all waves read ALL 4 partials in fixed order (bit-identical
//   z on every member) and run the RK4 epilogue redundantly.
// kbuf is double-buffered by ev&1: member program order is read(ev-1) ->
// write(ev) -> add(ev), so observing all add(ev) proves all read(ev-1) done —
// writing buf[(ev+1)&1] (= buf[(ev-1)&1]) can never race a reader.
// Deadlock-free without co-residency guarantees: non-members never wait on a
// group, finished groups release CUs. Spin has a bounded bailout (wrongness is
// visible in the harness; a hang is not).
__global__ __launch_bounds__(512) void ode_kernel(
    const float* __restrict__ z0, const float* __restrict__ tv,
    const float* __restrict__ b1, const float* __restrict__ b2,
    const _Float16* __restrict__ W1P, const _Float16* __restrict__ W2P,
    unsigned* flags, float* kbuf, float* __restrict__ out) {
    __shared__ _Float16 w2_lds[8 * 16 * 512];   // 128 KB: 8 waves x 16 tiles
    __shared__ _Float16 act_lds[16][264];       // 8.25 KB (+8 pad)
    __shared__ _Float16 z_lds[16][264];         // 8.25 KB

    const int tid  = threadIdx.x;
    const int w    = tid >> 6;
    const int lane = tid & 63;
    const int ln   = lane & 15;
    const int q    = lane >> 4;
    const int g    = blockIdx.x & 63;      // batch group: rows [g*16,+16)
    const int m    = blockIdx.x >> 6;      // member: H-slice [m*256,+256)
    const int m0   = g * 16;

    const float h = (tv[1] - tv[0]) * 0.125f;

    float bb1[2];
#pragma unroll
    for (int nt = 0; nt < 2; ++nt) bb1[nt] = b1[m * 256 + w * 32 + nt * 16 + ln];
    float bb2v[2];
#pragma unroll
    for (int t = 0; t < 2; ++t) bb2v[t] = b2[w * 32 + t * 16 + ln];

    // W1 slice -> registers, permanently (16 tiles = 64 VGPRs)
    const _Float16* w1base = W1P + (size_t)((m * 8 + w) * 16) * 512;
    f16x8 wreg[16];
#pragma unroll
    for (int i = 0; i < 16; ++i)
        wreg[i] = *(const f16x8*)(w1base + i * 512 + lane * 8);

    // W2 slice -> LDS, once (16 tiles/wave via async DMA; linear dest)
    const _Float16* w2base = W2P + (size_t)((m * 8 + w) * 16) * 512;
#pragma unroll
    for (int i = 0; i < 16; ++i)
        async_tile(w2base + i * 512, &w2_lds[(w * 16 + i) * 512], lane);

    // RK4 state (C-layout): z[t][r] = z[m0+q*4+r][w*32+t*16+ln]
    f32x4 z[2], zsum[2];
#pragma unroll
    for (int t = 0; t < 2; ++t)
#pragma unroll
        for (int r = 0; r < 4; ++r)
            z[t][r] = z0[(m0 + q * 4 + r) * Dd + w * 32 + t * 16 + ln];
#pragma unroll
    for (int t = 0; t < 2; ++t)
#pragma unroll
        for (int r = 0; r < 4; ++r)
            z_lds[q * 4 + r][w * 32 + t * 16 + ln] = (_Float16)z[t][r];
    __syncthreads();   // drains the W2 DMA (vmcnt) and publishes z_lds

    unsigned* flg = &flags[g];
    const size_t kstride = 16 * 256;                       // one member partial
    float* kb_grp[2];
    kb_grp[0] = kbuf + (size_t)g * 4 * kstride;            // buffer ev&1==0
    kb_grp[1] = kbuf + (size_t)(64 + g) * 4 * kstride;     // buffer ev&1==1

#pragma unroll 1
    for (int ev = 0; ev < 32; ++ev) {
        const int e = ev & 3;

        // ---- GEMM1: act = tanh(z @ W1_m + b1), B from registers ----
        f32x4 acc0 = {0.f, 0.f, 0.f, 0.f}, acc1 = {0.f, 0.f, 0.f, 0.f};
#pragma unroll
        for (int kk = 0; kk < 8; ++kk) {
            f16x8 a1 = *(const f16x8*)&z_lds[ln][kk * 32 + q * 8];
            acc0 = __builtin_amdgcn_mfma_f32_16x16x32_f16(a1, wreg[kk * 2 + 0], acc0, 0, 0, 0);
            acc1 = __builtin_amdgcn_mfma_f32_16x16x32_f16(a1, wreg[kk * 2 + 1], acc1, 0, 0, 0);
        }
#pragma unroll
        for (int r = 0; r < 4; ++r) {
            float x0 = acc0[r] + bb1[0];
            float e0 = __expf(2.0f * x0);
            act_lds[q * 4 + r][w * 32 + ln] = (_Float16)(1.0f - 2.0f / (e0 + 1.0f));
            float x1 = acc1[r] + bb1[1];
            float e1 = __expf(2.0f * x1);
            act_lds[q * 4 + r][w * 32 + 16 + ln] = (_Float16)(1.0f - 2.0f / (e1 + 1.0f));
        }
        __syncthreads();   // act visible

        // ---- GEMM2: partial k = act @ W2_m, B from LDS ----
        f32x4 acc2[2] = {{0.f, 0.f, 0.f, 0.f}, {0.f, 0.f, 0.f, 0.f}};
#pragma unroll
        for (int kk = 0; kk < 8; ++kk) {
            f16x8 a2 = *(const f16x8*)&act_lds[ln][kk * 32 + q * 8];
#pragma unroll
            for (int t = 0; t < 2; ++t) {
                f16x8 bf = *(const f16x8*)&w2_lds[(w * 16 + kk * 2 + t) * 512 + lane * 8];
                acc2[t] = __builtin_amdgcn_mfma_f32_16x16x32_f16(a2, bf, acc2[t], 0, 0, 0);
            }
        }

        // ---- exchange: write own partial, group-sync, read all 4 ----
        float* kb = kb_grp[ev & 1] + (size_t)m * kstride;
#pragma unroll
        for (int t = 0; t < 2; ++t)
#pragma unroll
            for (int r = 0; r < 4; ++r)
                kb[(q * 4 + r) * 256 + w * 32 + t * 16 + ln] = acc2[t][r];
        __syncthreads();   // each wave drains its stores (vmcnt 0) before flag
        if (tid == 0) {
            __threadfence();               // release: writeback to coherent point
            atomicAdd(flg, 1u);
            const unsigned target = 4u * (unsigned)(ev + 1);
            int guard = 0;
            while (atomicAdd(flg, 0u) < target && ++guard < (1 << 22))
                __builtin_amdgcn_s_sleep(2);
            __threadfence();               // acquire: invalidate stale L1/L2
        }
        __syncthreads();

        f32x4 kv[2] = {{0.f, 0.f, 0.f, 0.f}, {0.f, 0.f, 0.f, 0.f}};
        const float* kb0 = kb_grp[ev & 1];
#pragma unroll
        for (int mm = 0; mm < 4; ++mm)     // fixed order: identical z everywhere
#pragma unroll
            for (int t = 0; t < 2; ++t)
#pragma unroll
                for (int r = 0; r < 4; ++r)
                    kv[t][r] += kb0[mm * kstride + (q * 4 + r) * 256 + w * 32 + t * 16 + ln];

        // ---- RK4 epilogue (registers) ----
#pragma unroll
        for (int t = 0; t < 2; ++t) {
            f32x4 kvt, za;
#pragma unroll
            for (int r = 0; r < 4; ++r) kvt[r] = kv[t][r] + bb2v[t];
            if (e == 0) {
                zsum[t] = kvt;
            } else if (e == 3) {
#pragma unroll
                for (int r = 0; r < 4; ++r) zsum[t][r] += kvt[r];
            } else {
#pragma unroll
                for (int r = 0; r < 4; ++r) zsum[t][r] += 2.0f * kvt[r];
            }
            if (e < 3) {
                const float c = (e == 2) ? h : 0.5f * h;
#pragma unroll
                for (int r = 0; r < 4; ++r) za[r] = z[t][r] + c * kvt[r];
            } else {
#pragma unroll
                for (int r = 0; r < 4; ++r) {
                    z[t][r] += (h * (1.0f / 6.0f)) * zsum[t][r];
                    za[r] = z[t][r];
                }
            }
#pragma unroll
            for (int r = 0; r < 4; ++r)
                z_lds[q * 4 + r][w * 32 + t * 16 + ln] = (_Float16)za[r];
        }
        __syncthreads();   // z ready for next eval
    }

    if (m == 0) {
#pragma unroll
        for (int t = 0; t < 2; ++t)
#pragma unroll
            for (int r = 0; r < 4; ++r)
                out[(m0 + q * 4 + r) * Dd + w * 32 + t * 16 + ln] = z[t][r];
    }
}

extern "C" void kernel_launch(void* const* d_in, const int* in_sizes, int n_in,
                              void* d_out, int out_size, void* d_ws, size_t ws_size,
                              hipStream_t stream) {
    const float* z0 = (const float*)d_in[0];
    const float* tv = (const float*)d_in[1];
    const float* W1 = (const float*)d_in[2];   // [256][1024]
    const float* b1 = (const float*)d_in[3];   // [1024]
    const float* W2 = (const float*)d_in[4];   // [1024][256]
    const float* b2 = (const float*)d_in[5];   // [256]
    float* out = (float*)d_out;

    char* ws = (char*)d_ws;
    _Float16* W1P  = (_Float16*)ws;                         // 512 KB
    _Float16* W2P  = (_Float16*)(ws + (512 << 10));         // 512 KB
    unsigned* flags = (unsigned*)(ws + (1 << 20));          // 256 B (4 KB slot)
    float*    kbuf  = (float*)(ws + (1 << 20) + 4096);      // 2*64*4*16*256*4 = 8 MB

    pack_w1_kernel<<<1024, 256, 0, stream>>>(W1, W1P);
    pack_w2_kernel<<<1024, 256, 0, stream>>>(W2, W2P);
    reset_flags_kernel<<<1, 64, 0, stream>>>(flags);

    ode_kernel<<<256, 512, 0, stream>>>(z0, tv, b1, b2, W1P, W2P, flags, kbuf, out);
}

// Round 6
// 645.069 us; speedup vs baseline: 1.0531x; 1.0230x over previous
//
#include <hip/hip_runtime.h>

typedef _Float16 f16x8 __attribute__((ext_vector_type(8)));
typedef float f32x4 __attribute__((ext_vector_type(4)));

#define Dd 256
#define Hh 1024

// ---------- prep: pack weights fragment-major for the 16-wave layout ----------
// Wave w owns H-cols [w*64,+64) (GEMM1: nt=0..3) and D-cols [w*16,+16) (GEMM2).
// W1P chunk (w,c), c=0..15: kk=c>>1, nt pair (c&1)*2..+1. Tile i of chunk:
//   lane(q*16+ln) elem j holds W1[kk*32+q*8+j][w*64 + ((c&1)*2+i)*16 + ln]
__global__ void pack_w1_kernel(const float* __restrict__ W1, _Float16* __restrict__ W1P) {
    int gid = blockIdx.x * 256 + threadIdx.x;       // 256*1024 elements
    int h = gid & 1023, d = gid >> 10;
    int w = h >> 6, nt = (h >> 4) & 3, ln = h & 15;
    int kk = d >> 5, q = (d >> 3) & 3, j = d & 7;
    int c = kk * 2 + (nt >> 1), i = nt & 1;
    W1P[(((w * 16 + c) * 2 + i) * 64 + q * 16 + ln) * 8 + j] = (_Float16)W1[d * 1024 + h];
}
// W2P chunk (w,cp), cp=0..15: kk2 pair {2cp,2cp+1}. Tile i:
//   lane(q*16+ln) elem j holds W2[(2cp+i)*32+q*8+j][w*16+ln]
__global__ void pack_w2_kernel(const float* __restrict__ W2, _Float16* __restrict__ W2P) {
    int gid = blockIdx.x * 256 + threadIdx.x;       // 1024*256 elements
    int dcol = gid & 255, hh = gid >> 8;
    int kk2 = hh >> 5, q = (hh >> 3) & 3, j = hh & 7;
    int w = dcol >> 4, ln = dcol & 15;
    int cp = kk2 >> 1, i = kk2 & 1;
    W2P[(((w * 16 + cp) * 2 + i) * 64 + q * 16 + ln) * 8 + j] = (_Float16)W2[hh * 256 + dcol];
}

typedef __attribute__((address_space(1))) const unsigned int gu32;
typedef __attribute__((address_space(3))) unsigned int lu32;

// async 1KB fragment tile: global (per-lane base+lane*16) -> LDS (uniform base,
// HW scatters lane*16). Zero VGPR cost; tracked by vmcnt.
__device__ __forceinline__ void async_tile(const _Float16* g, _Float16* l, int lane) {
    __builtin_amdgcn_global_load_lds((gu32*)(g + lane * 8), (lu32*)l, 16, 0, 0);
}

// ---------------- main: 64 blocks x 1024 thr (16 waves), async-LDS weight ring ----------------
// Rounds 0-5 evidence: all streaming schedules at 8 waves/CU land at
// ~15 us/eval = 1 MB/eval/CU / ~30 B/cyc; m56 shows ~60 B/cyc/CU at higher
// occupancy => the lever is resident waves, not schedule. Round 4's 16-wave
// attempt died to a codegen artifact: plain __launch_bounds__(1024) let the
// allocator target 8 waves/EU (64-VGPR budget) and demote the register ring to
// scratch. Fix here: (a) LDS ring via global_load_lds = zero ring VGPRs,
// per-wave demand ~100 < 128; (b) __launch_bounds__(1024, 4) pins min 4
// waves/EU = 1 block/CU = 128-VGPR budget exactly.
// Per eval each wave streams 32 chunks (2 KB = 2 fragment tiles): 16 W1 + 16
// W2, via a 3-slot LDS ring. RAW: counted s_waitcnt vmcnt(4/2/0). WAR (slot
// overwritten by ISSUE(c+3) is the one chunk c was just read from): the
// lgkmcnt(0) guard at the top of ISSUE retires all prior ds_reads before the
// DMA can issue; its memory clobber stops the compiler hoisting the DMA above
// the reads. Accumulation order per output column (kk ascending) matches all
// previous passing kernels => identical numerics.
__global__ __launch_bounds__(1024, 4) void ode_kernel(
    const float* __restrict__ z0, const float* __restrict__ tv,
    const float* __restrict__ b1, const float* __restrict__ b2,
    const _Float16* __restrict__ W1P, const _Float16* __restrict__ W2P,
    float* __restrict__ out) {
    __shared__ _Float16 wbuf[16][3][1024];   // 96 KB: per-wave 3-slot ring
    __shared__ _Float16 act_lds[16][1032];   // 33 KB (+8 pad)
    __shared__ _Float16 z_lds[16][264];      // 8.25 KB

    const int tid  = threadIdx.x;
    const int w    = tid >> 6;               // 0..15
    const int lane = tid & 63;
    const int ln   = lane & 15;
    const int q    = lane >> 4;
    const int m0   = blockIdx.x * 16;

    const float h = (tv[1] - tv[0]) * 0.125f;

    float bb1[4];
#pragma unroll
    for (int nt = 0; nt < 4; ++nt) bb1[nt] = b1[w * 64 + nt * 16 + ln];
    const float bb2 = b2[w * 16 + ln];

    const _Float16* W1w = W1P + (size_t)w * 16384;   // 32 KB: 16 chunks (kk,ntpair)
    const _Float16* W2w = W2P + (size_t)w * 16384;   // 32 KB: 16 chunks (kk2 pair)

// chunk g (0..31): g<16 => W1 chunk g; g>=16 => W2 chunk g-16. Dest slot g%3.
// lgkmcnt(0) guard: all prior ds_reads retired before DMA overwrite (WAR fix).
#define ISSUE(gg) { asm volatile("s_waitcnt lgkmcnt(0)" ::: "memory");               \
    const _Float16* gsrc = ((gg) < 16) ? (W1w + (gg) * 1024)                         \
                                       : (W2w + ((gg) - 16) * 1024);                 \
    _Float16* ldst = &wbuf[w][(gg) % 3][0];                                          \
    async_tile(gsrc, ldst, lane);                                                    \
    async_tile(gsrc + 512, ldst + 512, lane); }
// before consuming chunk gg: oldest outstanding chunk must have landed
// (2 async ops per chunk; up to 2 younger chunks in flight)
#define WAITC(gg) { if ((gg) <= 29)      asm volatile("s_waitcnt vmcnt(4)" ::: "memory"); \
                    else if ((gg) == 30) asm volatile("s_waitcnt vmcnt(2)" ::: "memory"); \
                    else                 asm volatile("s_waitcnt vmcnt(0)" ::: "memory"); }
// act/z publish: retire ds_writes, then barrier (in-flight DMA survives)
#define BARRIER() asm volatile("s_waitcnt lgkmcnt(0)\n\ts_barrier" ::: "memory")

    // RK4 state (C-layout): z[r] = z[m0+q*4+r][w*16+ln]
    f32x4 z, zsum;
#pragma unroll
    for (int r = 0; r < 4; ++r)
        z[r] = z0[(m0 + q * 4 + r) * Dd + w * 16 + ln];
#pragma unroll
    for (int r = 0; r < 4; ++r)
        z_lds[q * 4 + r][w * 16 + ln] = (_Float16)z[r];
    __syncthreads();

#pragma unroll 1
    for (int ev = 0; ev < 32; ++ev) {
        const int e = ev & 3;

        // prime the ring (end-of-eval barrier drained previous eval's traffic)
        ISSUE(0); ISSUE(1); ISSUE(2);

        // ---- GEMM1: act[:, w*64..+64) = tanh(z @ W1 + b1) ----
        f16x8 a1[8];
#pragma unroll
        for (int kk = 0; kk < 8; ++kk)
            a1[kk] = *(const f16x8*)&z_lds[ln][kk * 32 + q * 8];

        f32x4 acc[4] = {{0.f,0.f,0.f,0.f},{0.f,0.f,0.f,0.f},
                        {0.f,0.f,0.f,0.f},{0.f,0.f,0.f,0.f}};
#pragma unroll
        for (int c = 0; c < 16; ++c) {       // chunk c: kk=c>>1, nt (c&1)*2..+1
            WAITC(c);
            const _Float16* tb = &wbuf[w][c % 3][0];
            const int kk = c >> 1, nb = (c & 1) * 2;
            f16x8 bf0 = *(const f16x8*)&tb[lane * 8];
            f16x8 bf1 = *(const f16x8*)&tb[512 + lane * 8];
            acc[nb + 0] = __builtin_amdgcn_mfma_f32_16x16x32_f16(a1[kk], bf0, acc[nb + 0], 0, 0, 0);
            acc[nb + 1] = __builtin_amdgcn_mfma_f32_16x16x32_f16(a1[kk], bf1, acc[nb + 1], 0, 0, 0);
            ISSUE(c + 3);                    // c=13..15 issue W2 chunks 16..18
        }
#pragma unroll
        for (int nt = 0; nt < 4; ++nt)
#pragma unroll
            for (int r = 0; r < 4; ++r) {
                float x = acc[nt][r] + bb1[nt];
                float ex = __expf(2.0f * x);
                act_lds[q * 4 + r][w * 64 + nt * 16 + ln] =
                    (_Float16)(1.0f - 2.0f / (ex + 1.0f));
            }
        BARRIER();   // act visible; W2 chunks 16..18 remain in flight

        // ---- GEMM2: k[:, w*16..+16) = act @ W2 + b2 ----
        f32x4 acc2 = {0.f, 0.f, 0.f, 0.f};
#pragma unroll
        for (int cp = 0; cp < 16; ++cp) {
            const int g = 16 + cp;           // chunk: kk2 pair {2cp,2cp+1}
            WAITC(g);
            const _Float16* tb = &wbuf[w][g % 3][0];
#pragma unroll
            for (int i = 0; i < 2; ++i) {
                const int kk2 = cp * 2 + i;
                f16x8 a2 = *(const f16x8*)&act_lds[ln][kk2 * 32 + q * 8];
                f16x8 bf = *(const f16x8*)&tb[i * 512 + lane * 8];
                acc2 = __builtin_amdgcn_mfma_f32_16x16x32_f16(a2, bf, acc2, 0, 0, 0);
            }
            if (g + 3 <= 31) ISSUE(g + 3);
        }

        // ---- RK4 epilogue (registers) ----
        f32x4 kv, za;
#pragma unroll
        for (int r = 0; r < 4; ++r) kv[r] = acc2[r] + bb2;
        if (e == 0) {
            zsum = kv;
        } else if (e == 3) {
#pragma unroll
            for (int r = 0; r < 4; ++r) zsum[r] += kv[r];
        } else {
#pragma unroll
            for (int r = 0; r < 4; ++r) zsum[r] += 2.0f * kv[r];
        }
        if (e < 3) {
            const float c = (e == 2) ? h : 0.5f * h;
#pragma unroll
            for (int r = 0; r < 4; ++r) za[r] = z[r] + c * kv[r];
        } else {
#pragma unroll
            for (int r = 0; r < 4; ++r) {
                z[r] += (h * (1.0f / 6.0f)) * zsum[r];
                za[r] = z[r];
            }
        }
#pragma unroll
        for (int r = 0; r < 4; ++r)
            z_lds[q * 4 + r][w * 16 + ln] = (_Float16)za[r];
        BARRIER();   // z ready for next eval (ring fully drained by WAITC(31))
    }

#pragma unroll
    for (int r = 0; r < 4; ++r)
        out[(m0 + q * 4 + r) * Dd + w * 16 + ln] = z[r];
#undef ISSUE
#undef WAITC
#undef BARRIER
}

extern "C" void kernel_launch(void* const* d_in, const int* in_sizes, int n_in,
                              void* d_out, int out_size, void* d_ws, size_t ws_size,
                              hipStream_t stream) {
    const float* z0 = (const float*)d_in[0];
    const float* tv = (const float*)d_in[1];
    const float* W1 = (const float*)d_in[2];   // [256][1024]
    const float* b1 = (const float*)d_in[3];   // [1024]
    const float* W2 = (const float*)d_in[4];   // [1024][256]
    const float* b2 = (const float*)d_in[5];   // [256]
    float* out = (float*)d_out;

    _Float16* W1P = (_Float16*)d_ws;           // 512 KB fragment-major
    _Float16* W2P = W1P + Hh * Dd;             // 512 KB fragment-major

    pack_w1_kernel<<<1024, 256, 0, stream>>>(W1, W1P);
    pack_w2_kernel<<<1024, 256, 0, stream>>>(W2, W2P);

    ode_kernel<<<64, 1024, 0, stream>>>(z0, tv, b1, b2, W1P, W2P, out);
}